// Round 10
// baseline (526.664 us; speedup 1.0000x reference)
//
#include <hip/hip_runtime.h>

#define TT  1024
#define DIN 8

// sigma(x) = 1 / (1 + exp2(-x*log2e))
__device__ __forceinline__ float fsig(float x) {
    float e = __builtin_amdgcn_exp2f(-1.4426950408889634f * x);
    return __builtin_amdgcn_rcpf(1.0f + e);
}
// tanh(x) = 2*sigma(2x) - 1
__device__ __forceinline__ float ftanh_(float x) {
    float e = __builtin_amdgcn_exp2f(-2.8853900817779268f * x);
    return 2.0f * __builtin_amdgcn_rcpf(1.0f + e) - 1.0f;
}
// DPP lane permute, compile-time ctrl. 0xB1 = quad_perm(1,0,3,2) (swap 2k<->2k+1)
// 0x114 = row_shr:4 (lane i <- i-4), 0x112 = row_shr:2, 0x102 = row_shl:2 (i <- i+2)
template<int CTRL>
__device__ __forceinline__ float dppf(float v) {
    return __uint_as_float((unsigned)__builtin_amdgcn_update_dpp(
        0, (int)__float_as_uint(v), CTRL, 0xF, 0xF, true));
}
// lgkm-only barrier: ds_writes visible + ds_reads of old parity slot complete.
// Global out-stores (never read back) and the 8 in-flight x prefetches stay
// outstanding across it — REQUIRED for the deep prefetch to work at all
// (__syncthreads' vmcnt(0) would serialize all 8 loads once per tile).
__device__ __forceinline__ void bar_lgkm() {
    asm volatile("s_waitcnt lgkmcnt(0)\n\ts_barrier" ::: "memory");
}

// One pipeline step; COMPILE-TIME parity P0 = t&1, x-slot XS = t&7.
// Consumes xq[XS] (loaded 8 steps ago -> ~7000 cy slack vs ~900 cy worst-case
// HBM latency), then re-issues a load of x(t+8) into the same slot.
#define STEP(TCUR, P0, XS)                                                     \
  {                                                                            \
    const int tcu = (TCUR);                                                    \
    if (isL1) {                                                                \
      if (tcu < TT) {                                                          \
        const float* hin = &hb1[P0 ^ 1][part << 4];                            \
        float a0 = bias, a1 = 0.f, a2 = 0.f, a3 = 0.f;                         \
        _Pragma("unroll")                                                      \
        for (int qq = 0; qq < 4; ++qq) {                                       \
          float4 v = reinterpret_cast<const float4*>(hin)[qq];                 \
          a0 += wg[4*qq]  *v.x; a1 += wg[4*qq+1]*v.y;                          \
          a2 += wg[4*qq+2]*v.z; a3 += wg[4*qq+3]*v.w;                          \
        }                                                                      \
        a0 += wg[16]*xq[XS].x; a1 += wg[17]*xq[XS].y;                          \
        a2 += wg[18]*xq[XS].z; a3 += wg[19]*xq[XS].w;                          \
        xq[XS] = *reinterpret_cast<const float4*>(xb + xnt + part4);           \
        xnt  = (xnt + DIN > XMAX) ? XMAX : (xnt + DIN);                        \
        float sum  = (a0 + a1) + (a2 + a3);                                    \
        float full = sum + dppf<0xB1>(sum);                                    \
        float u  = isg ? (full + full) : full;                                 \
        float S  = fsig(u);                                                    \
        float av = isg ? (S + S - 1.0f) : S;                                   \
        float itg = dppf<0x114>(av) * av;                                      \
        float fv  = dppf<0x112>(av);                                           \
        c = fv * c + itg;                                                      \
        float so  = dppf<0x102>(av);                                           \
        float hv  = so * ftanh_(c);                                            \
        if ((l & 7) == 4) hb1[P0][unit] = hv;                                  \
      }                                                                        \
      if (tcu >= 2) {                                                          \
        const float* hob = &hb2[P0][part << 4];                                \
        float o0 = obias, o1 = 0.f, o2 = 0.f, o3 = 0.f;                        \
        _Pragma("unroll")                                                      \
        for (int qq = 0; qq < 4; ++qq) {                                       \
          float4 v = reinterpret_cast<const float4*>(hob)[qq];                 \
          o0 += wl[4*qq]  *v.x; o1 += wl[4*qq+1]*v.y;                          \
          o2 += wl[4*qq+2]*v.z; o3 += wl[4*qq+3]*v.w;                          \
        }                                                                      \
        float osum  = (o0 + o1) + (o2 + o3);                                   \
        float ofull = osum + dppf<0xB1>(osum);                                 \
        if (!part && l < 40) outb[t80 + ocol] = ofull;                         \
        t80 += 80;                                                             \
      }                                                                        \
    } else {                                                                   \
      if (tcu >= 1 && tcu <= TT) {                                             \
        const float* hin = part ? &hb1[P0 ^ 1][0] : &hb2[P0][0];               \
        float a0 = bias, a1 = 0.f, a2 = 0.f, a3 = 0.f;                         \
        _Pragma("unroll")                                                      \
        for (int qq = 0; qq < 8; ++qq) {                                       \
          float4 v = reinterpret_cast<const float4*>(hin)[qq];                 \
          a0 += wg2[4*qq]  *v.x; a1 += wg2[4*qq+1]*v.y;                        \
          a2 += wg2[4*qq+2]*v.z; a3 += wg2[4*qq+3]*v.w;                        \
        }                                                                      \
        float sum  = (a0 + a1) + (a2 + a3);                                    \
        float full = sum + dppf<0xB1>(sum);                                    \
        float u  = isg ? (full + full) : full;                                 \
        float S  = fsig(u);                                                    \
        float av = isg ? (S + S - 1.0f) : S;                                   \
        float itg = dppf<0x114>(av) * av;                                      \
        float fv  = dppf<0x112>(av);                                           \
        c = fv * c + itg;                                                      \
        float so  = dppf<0x102>(av);                                           \
        float hv  = so * ftanh_(c);                                            \
        if ((l & 7) == 4) hb2[P0 ^ 1][unit] = hv;                              \
      }                                                                        \
    }                                                                          \
    bar_lgkm();                                                                \
  }

// 8 waves / batch element (block=512), layer-pipelined, 2 lanes per gate row.
// Lane l: ul=l>>3 (unit-local 0..7), g=(l>>1)&3 (i,f,g,o), part=l&1.
// Waves 0-3: layer 1 (16 h-wts + 4 x-wts per lane) + out-linear (16 wts,
//            col = wu*20 + l>>1, lanes<40), out runs 2 steps behind.
// Waves 4-7: layer 2 (32 wts: part0 = Whh2 row (h2 input), part1 = Wih2 (h1)).
// Half-sums combined via DPP quad_perm; cell update via DPP row_shr4/shr2/shl2
// onto the g-lanes (l&7 in {4,5}); lane l&7==4 publishes h to LDS.
// Pipeline at iter t: L1 -> h1(t); L2 -> h2(t-1); out(t-2). One barrier/iter.
__global__ void __launch_bounds__(512, 2)
lstm_pipe10(const float* __restrict__ x,
            const float* __restrict__ Wih1, const float* __restrict__ Whh1,
            const float* __restrict__ bih1, const float* __restrict__ bhh1,
            const float* __restrict__ Wih2, const float* __restrict__ Whh2,
            const float* __restrict__ bih2, const float* __restrict__ bhh2,
            const float* __restrict__ Wlin, const float* __restrict__ blin,
            float* __restrict__ out)
{
    const int tid  = threadIdx.x;
    const int wv   = tid >> 6;         // wave 0..7
    const int l    = tid & 63;
    const int part = l & 1;
    const int part4 = part * 4;
    const int g    = (l >> 1) & 3;     // 0=i 1=f 2=g 3=o
    const int ul   = l >> 3;           // unit-local 0..7
    const int b    = blockIdx.x;
    const bool isL1 = (wv < 4);
    const int  wu   = isL1 ? wv : (wv - 4);
    const int  unit = wu*8 + ul;       // hidden unit 0..31
    const int  R    = g*32 + unit;     // gate row 0..127
    const bool isg  = (g == 2);
    const int  XMAX = (TT - 1) * DIN;

    __shared__ float hb1[2][32];       // h1 by parity
    __shared__ float hb2[2][32];       // h2 by parity
    if (tid < 64)       ((float*)hb1)[tid]      = 0.f;
    else if (tid < 128) ((float*)hb2)[tid - 64] = 0.f;

    // ---- per-lane weights ----
    float wg[20];          // L1: [0:16]=Whh1 half, [16:20]=Wih1 quarter
    float wg2[32];         // L2: full 32 input wts
    float wl[16];          // L1: out-linear half column
    float bias = 0.f, obias = 0.f;
    int ocol = 0;

    if (isL1) {
        const float* wsrc = Whh1 + R*32 + part*16;
#pragma unroll
        for (int qq = 0; qq < 4; ++qq) {
            float4 v = reinterpret_cast<const float4*>(wsrc)[qq];
            wg[4*qq]=v.x; wg[4*qq+1]=v.y; wg[4*qq+2]=v.z; wg[4*qq+3]=v.w;
        }
        float4 xv = *reinterpret_cast<const float4*>(Wih1 + R*DIN + part4);
        wg[16]=xv.x; wg[17]=xv.y; wg[18]=xv.z; wg[19]=xv.w;
        if (!part) bias = bih1[R] + bhh1[R];
        ocol = wu*20 + (l >> 1);
        const int oc = (l < 40) ? ocol : 79;       // clamp: loads valid, unused
        const float* osrc = Wlin + oc*32 + part*16;
#pragma unroll
        for (int qq = 0; qq < 4; ++qq) {
            float4 v = reinterpret_cast<const float4*>(osrc)[qq];
            wl[4*qq]=v.x; wl[4*qq+1]=v.y; wl[4*qq+2]=v.z; wl[4*qq+3]=v.w;
        }
        if (!part) obias = blin[oc];
    } else {
        const float* wsrc = part ? (Wih2 + R*32) : (Whh2 + R*32);
#pragma unroll
        for (int qq = 0; qq < 8; ++qq) {
            float4 v = reinterpret_cast<const float4*>(wsrc)[qq];
            wg2[4*qq]=v.x; wg2[4*qq+1]=v.y; wg2[4*qq+2]=v.z; wg2[4*qq+3]=v.w;
        }
        if (!part) bias = bih2[R] + bhh2[R];
    }

    float c = 0.f;   // valid on lanes l&7 in {4,5}; bounded garbage elsewhere

    const float* __restrict__ xb = x   + (size_t)b * (TT*DIN);
    float* __restrict__ outb     = out + (size_t)b * (TT*80);

    // ---- 8-slot rotating x prefetch (L1 waves; 32 VGPRs) ----
    float4 xq[8];
    if (isL1) {
#pragma unroll
        for (int s = 0; s < 8; ++s)
            xq[s] = *reinterpret_cast<const float4*>(xb + s*DIN + part4);
    }
    int xnt = 8 * DIN;   // scalar: next prefetch target = x(8)
    int t80 = 0;         // scalar running out offset (floats)

    bar_lgkm();   // zero-init visible

#pragma unroll 1
    for (int tb = 0; tb < TT/8; ++tb) {
        const int t0 = 8*tb;
        STEP(t0 + 0, 0, 0)
        STEP(t0 + 1, 1, 1)
        STEP(t0 + 2, 0, 2)
        STEP(t0 + 3, 1, 3)
        STEP(t0 + 4, 0, 4)
        STEP(t0 + 5, 1, 5)
        STEP(t0 + 6, 0, 6)
        STEP(t0 + 7, 1, 7)
    }
    STEP(TT,     0, 0)    // drain: L2 computes h2(TT-1); out(TT-2)
    STEP(TT + 1, 1, 1)    // drain: out(TT-1)
}

extern "C" void kernel_launch(void* const* d_in, const int* in_sizes, int n_in,
                              void* d_out, int out_size, void* d_ws, size_t ws_size,
                              hipStream_t stream) {
    const float* x    = (const float*)d_in[0];
    const float* Wih1 = (const float*)d_in[1];
    const float* Whh1 = (const float*)d_in[2];
    const float* bih1 = (const float*)d_in[3];
    const float* bhh1 = (const float*)d_in[4];
    const float* Wih2 = (const float*)d_in[5];
    const float* Whh2 = (const float*)d_in[6];
    const float* bih2 = (const float*)d_in[7];
    const float* bhh2 = (const float*)d_in[8];
    const float* Wlin = (const float*)d_in[9];
    const float* blin = (const float*)d_in[10];

    const int B = in_sizes[0] / (TT * DIN);   // 256

    hipLaunchKernelGGL(lstm_pipe10, dim3(B), dim3(512), 0, stream,
                       x, Wih1, Whh1, bih1, bhh1,
                       Wih2, Whh2, bih2, bhh2, Wlin, blin,
                       (float*)d_out);
}

// Round 11
// 392.682 us; speedup vs baseline: 1.3412x; 1.3412x over previous
//
#include <hip/hip_runtime.h>

#define TT  1024
#define DIN 8

// sigma(x) = 1 / (1 + exp2(-x*log2e))
__device__ __forceinline__ float fsig(float x) {
    float e = __builtin_amdgcn_exp2f(-1.4426950408889634f * x);
    return __builtin_amdgcn_rcpf(1.0f + e);
}
// tanh(x) = 2*sigma(2x) - 1
__device__ __forceinline__ float ftanh_(float x) {
    float e = __builtin_amdgcn_exp2f(-2.8853900817779268f * x);
    return 2.0f * __builtin_amdgcn_rcpf(1.0f + e) - 1.0f;
}
// DPP lane permute, compile-time ctrl.
// 0xB1 = quad_perm(1,0,3,2): XOR-1. 0x4E = quad_perm(2,3,0,1): XOR-2.
// 0x114 = row_shr:4, 0x112 = row_shr:2, 0x102 = row_shl:2.
template<int CTRL>
__device__ __forceinline__ float dppf(float v) {
    return __uint_as_float((unsigned)__builtin_amdgcn_update_dpp(
        0, (int)__float_as_uint(v), CTRL, 0xF, 0xF, true));
}

// ============================ kernel 1: recurrence ============================
// 8 waves / batch element. Waves 0-3: layer 1 (R6 layout: 2 lanes/gate row,
// part = half of the 32-dot; 4 uniform b128 reads + 20 FMA). Waves 4-7:
// layer 2 QUAD-SPLIT: quad = {g,g^1}x{part}; each lane reads ONE (input,half)
// slice (4 b128 = 16 floats), computes 16+16 partials for its row-PAIR,
// 3-DPP reduction assembles both rows' full 64-dots. Cell update via DPP
// row_shr4/shr2/shl2 (R6-proven). h2(t) stored to out[b][t][0:32] (scratch)
// for kernel 2. One __syncthreads per timestep-iteration.
__global__ void __launch_bounds__(512, 2)
lstm_rec(const float* __restrict__ x,
         const float* __restrict__ Wih1, const float* __restrict__ Whh1,
         const float* __restrict__ bih1, const float* __restrict__ bhh1,
         const float* __restrict__ Wih2, const float* __restrict__ Whh2,
         const float* __restrict__ bih2, const float* __restrict__ bhh2,
         float* __restrict__ out)
{
    const int tid  = threadIdx.x;
    const int wv   = tid >> 6;         // wave 0..7
    const int l    = tid & 63;
    const int part = l & 1;
    const int g    = (l >> 1) & 3;     // 0=i 1=f 2=g 3=o
    const int ul   = l >> 3;           // unit-local 0..7
    const int b    = blockIdx.x;
    const bool isL1 = (wv < 4);
    const int  wu   = isL1 ? wv : (wv - 4);
    const int  unit = wu*8 + ul;       // hidden unit 0..31
    const bool isg  = (g == 2);

    __shared__ float hb1[2][32];       // h1 by parity
    __shared__ float hb2[2][32];       // h2 by parity
    if (tid < 64)       ((float*)hb1)[tid]      = 0.f;
    else if (tid < 128) ((float*)hb2)[tid - 64] = 0.f;

    // ---- per-lane weights ----
    float wg[20];                // L1: [0:16] Whh1 half, [16:20] Wih1 quarter
    float wA[16], wB[16];        // L2: 16 wts of even row, 16 of odd row
    float bias = 0.f;

    if (isL1) {
        const int R = g*32 + unit;
        const float* wsrc = Whh1 + R*32 + part*16;
#pragma unroll
        for (int qq = 0; qq < 4; ++qq) {
            float4 v = reinterpret_cast<const float4*>(wsrc)[qq];
            wg[4*qq]=v.x; wg[4*qq+1]=v.y; wg[4*qq+2]=v.z; wg[4*qq+3]=v.w;
        }
        float4 xv = *reinterpret_cast<const float4*>(Wih1 + R*DIN + part*4);
        wg[16]=xv.x; wg[17]=xv.y; wg[18]=xv.z; wg[19]=xv.w;
        if (!part) bias = bih1[R] + bhh1[R];
    } else {
        const int hs = g & 1;            // which 16-half of the input vector
        const int k2 = g >> 1;           // row-pair selector
        const int Re = (2*k2)*32 + unit;     // even row of pair
        const int Ro = (2*k2+1)*32 + unit;   // odd row of pair
        const int Rw = g*32 + unit;          // own row (bias)
        const float* base = part ? Wih2 : Whh2;  // part1: h1-input, part0: h2
#pragma unroll
        for (int qq = 0; qq < 4; ++qq) {
            float4 va = reinterpret_cast<const float4*>(base + Re*32 + hs*16)[qq];
            wA[4*qq]=va.x; wA[4*qq+1]=va.y; wA[4*qq+2]=va.z; wA[4*qq+3]=va.w;
            float4 vb = reinterpret_cast<const float4*>(base + Ro*32 + hs*16)[qq];
            wB[4*qq]=vb.x; wB[4*qq+1]=vb.y; wB[4*qq+2]=vb.z; wB[4*qq+3]=vb.w;
        }
        bias = bih2[Rw] + bhh2[Rw];      // added once, post-reduction (own row)
    }

    float c = 0.f;   // valid on lanes l&7 in {4,5}; bounded garbage elsewhere

    const float* __restrict__ xb = x   + (size_t)b * (TT*DIN);
    float* __restrict__ outb     = out + (size_t)b * (TT*80);

    float4 xcur;
    if (isL1) xcur = *reinterpret_cast<const float4*>(xb + part*4);  // x(0)
    int xoff = DIN;          // float offset of next x prefetch (t=1)
    int o2   = 0;            // running h2-store offset: (t-1)*80

    __syncthreads();   // zero-init visible

#pragma unroll 1
    for (int t = 0; t <= TT; ++t) {
        const int p0  = t & 1;
        const int pm1 = p0 ^ 1;

        if (isL1) {
            if (t < TT) {
                const float* hin = &hb1[pm1][part << 4];
                float a0 = bias, a1 = 0.f, a2 = 0.f, a3 = 0.f;
#pragma unroll
                for (int qq = 0; qq < 4; ++qq) {
                    float4 v = reinterpret_cast<const float4*>(hin)[qq];
                    a0 += wg[4*qq]  *v.x; a1 += wg[4*qq+1]*v.y;
                    a2 += wg[4*qq+2]*v.z; a3 += wg[4*qq+3]*v.w;
                }
                a0 += wg[16]*xcur.x; a1 += wg[17]*xcur.y;
                a2 += wg[18]*xcur.z; a3 += wg[19]*xcur.w;
                xcur = *reinterpret_cast<const float4*>(xb + xoff + part*4);
                xoff = (xoff + DIN > (TT-1)*DIN) ? (TT-1)*DIN : (xoff + DIN);

                float sum  = (a0 + a1) + (a2 + a3);
                float full = sum + dppf<0xB1>(sum);      // combine part-halves
                float u  = isg ? (full + full) : full;
                float S  = fsig(u);
                float av = isg ? (S + S - 1.0f) : S;     // tanh(g) | sigmoid
                float itg = dppf<0x114>(av) * av;        // sig(i)*tanh(g)
                float fv  = dppf<0x112>(av);             // sig(f)
                c = fv * c + itg;
                float so  = dppf<0x102>(av);             // sig(o)
                float hv  = so * ftanh_(c);
                if ((l & 7) == 4) hb1[p0][unit] = hv;    // publish h1(t)
            }
        } else {
            if (t >= 1) {
                // quad-split read: 16 floats of (input=part, half=g&1)
                const int hs = g & 1;
                const float* hin = part ? &hb1[pm1][hs << 4] : &hb2[p0][hs << 4];
                float4 hv4[4];
#pragma unroll
                for (int qq = 0; qq < 4; ++qq)
                    hv4[qq] = reinterpret_cast<const float4*>(hin)[qq];
                // partials for BOTH rows of the pair over my 16-slice
                float e0 = 0.f, e1 = 0.f, o0 = 0.f, o1 = 0.f;
#pragma unroll
                for (int qq = 0; qq < 4; ++qq) {
                    e0 += wA[4*qq]  *hv4[qq].x; e1 += wA[4*qq+1]*hv4[qq].y;
                    e0 += wA[4*qq+2]*hv4[qq].z; e1 += wA[4*qq+3]*hv4[qq].w;
                    o0 += wB[4*qq]  *hv4[qq].x; o1 += wB[4*qq+1]*hv4[qq].y;
                    o0 += wB[4*qq+2]*hv4[qq].z; o1 += wB[4*qq+3]*hv4[qq].w;
                }
                float accE = e0 + e1;    // row even (of pair), my (part,hs)
                float accO = o0 + o1;    // row odd
                // step 1 (XOR-1, other input, same hs): combine h1+h2 partials
                accE += dppf<0xB1>(accE);
                accO += dppf<0xB1>(accO);
                // step 2 (XOR-2, other hs & other row-owner): swap complements
                float stage = hs ? accE : accO;   // what partner needs
                float recv  = dppf<0x4E>(stage);  // partner's complement of MY row
                float own   = hs ? accO : accE;
                float full  = own + recv + bias;  // my row's complete 64-dot

                float u  = isg ? (full + full) : full;
                float S  = fsig(u);
                float av = isg ? (S + S - 1.0f) : S;
                float itg = dppf<0x114>(av) * av;
                float fv  = dppf<0x112>(av);
                c = fv * c + itg;
                float so  = dppf<0x102>(av);
                float hv  = so * ftanh_(c);
                if ((l & 7) == 4) {
                    hb2[pm1][unit] = hv;          // publish h2(t-1) for L2
                    outb[o2 + unit] = hv;         // scratch h2 for kernel 2
                }
                o2 += 80;
            }
        }

        __syncthreads();
    }
}

// ============================ kernel 2: out linear ============================
// out[row][0:80] = h2[row] @ Wlin^T + blin, h2 scratch = out[row][0:32].
// Block 256: stage Wlin (80x32) + bias once; grid-stride over 16-row tiles.
// Thread (row = tid>>4, cl = tid&15) computes cols cl, cl+16, ..., cl+64.
// Pads (stride 36) keep LDS reads <=2-way-conflict (free).
__global__ void __launch_bounds__(256, 4)
out_lin(const float* __restrict__ Wlin, const float* __restrict__ blin,
        float* __restrict__ out, int ntiles)
{
    __shared__ float wl[80][36];
    __shared__ float bl[80];
    __shared__ float ht[16][36];
    const int tid = threadIdx.x;

#pragma unroll 1
    for (int i = tid; i < 640; i += 256) {          // 80 rows x 8 float4
        const int cc = i >> 3, qq = i & 7;
        float4 v = reinterpret_cast<const float4*>(Wlin)[i];
        *reinterpret_cast<float4*>(&wl[cc][qq*4]) = v;
    }
    if (tid < 80) bl[tid] = blin[tid];
    __syncthreads();

    const int row = tid >> 4;   // 0..15
    const int cl  = tid & 15;   // 0..15

#pragma unroll 1
    for (int tile = blockIdx.x; tile < ntiles; tile += gridDim.x) {
        const size_t base = (size_t)tile * 16;
        if (tid < 128) {                            // stage 16 rows of h2
            const int r = tid >> 3, qq = tid & 7;
            float4 v = *reinterpret_cast<const float4*>(out + (base + r)*80 + qq*4);
            *reinterpret_cast<float4*>(&ht[r][qq*4]) = v;
        }
        __syncthreads();

        float hr[32];
#pragma unroll
        for (int j = 0; j < 8; ++j) {
            float4 v = *reinterpret_cast<const float4*>(&ht[row][j*4]);
            hr[4*j]=v.x; hr[4*j+1]=v.y; hr[4*j+2]=v.z; hr[4*j+3]=v.w;
        }
        float res[5];
#pragma unroll
        for (int cj = 0; cj < 5; ++cj) {
            const int cc = cl + 16*cj;
            float a0 = bl[cc], a1 = 0.f, a2 = 0.f, a3 = 0.f;
#pragma unroll
            for (int k = 0; k < 32; k += 4) {
                a0 += wl[cc][k]  *hr[k];   a1 += wl[cc][k+1]*hr[k+1];
                a2 += wl[cc][k+2]*hr[k+2]; a3 += wl[cc][k+3]*hr[k+3];
            }
            res[cj] = (a0 + a1) + (a2 + a3);
        }
        __syncthreads();   // ht reads complete before next tile's staging
#pragma unroll
        for (int cj = 0; cj < 5; ++cj)
            out[(base + row)*80 + cl + 16*cj] = res[cj];
    }
}

extern "C" void kernel_launch(void* const* d_in, const int* in_sizes, int n_in,
                              void* d_out, int out_size, void* d_ws, size_t ws_size,
                              hipStream_t stream) {
    const float* x    = (const float*)d_in[0];
    const float* Wih1 = (const float*)d_in[1];
    const float* Whh1 = (const float*)d_in[2];
    const float* bih1 = (const float*)d_in[3];
    const float* bhh1 = (const float*)d_in[4];
    const float* Wih2 = (const float*)d_in[5];
    const float* Whh2 = (const float*)d_in[6];
    const float* bih2 = (const float*)d_in[7];
    const float* bhh2 = (const float*)d_in[8];
    const float* Wlin = (const float*)d_in[9];
    const float* blin = (const float*)d_in[10];

    const int B = in_sizes[0] / (TT * DIN);   // 256
    const int ntiles = (B * TT) / 16;         // 16384

    hipLaunchKernelGGL(lstm_rec, dim3(B), dim3(512), 0, stream,
                       x, Wih1, Whh1, bih1, bhh1,
                       Wih2, Whh2, bih2, bhh2,
                       (float*)d_out);
    hipLaunchKernelGGL(out_lin, dim3(2048), dim3(256), 0, stream,
                       Wlin, blin, (float*)d_out, ntiles);
}